// Round 13
// baseline (1101.811 us; speedup 1.0000x reference)
//
#include <hip/hip_runtime.h>
#include <hip/hip_bf16.h>

typedef __attribute__((ext_vector_type(8))) short short8v;   // bf16x8 fragment
typedef __attribute__((ext_vector_type(4))) float float4v;   // fp32x4 accum
typedef unsigned short ushort;
typedef unsigned int uint;

namespace {

constexpr int Hh = 192, Ww = 192, Cc = 16, Oo = 64, Bb = 4;
constexpr int TH = 4, TW = 32, NT = 128;     // 4x32 pixel tile, 128 threads (2 waves)
constexpr int HW = Hh * Ww;                  // 36864
constexpr size_t PLANE = (size_t)Bb * Oo * HW;        // 9437184 floats per partial

// Each feature = (vertical segment sum) + (horizontal segment sum), scaled by 1/n.
struct FD { int hasV; int vdj, vi0, vi1; int hasH; int hdi, hj0, hj1; float inv_n; };

constexpr FD FT[49] = {
    // 9 inner taps (i,j) row-major, n=1
    {1,-1,-1,-1, 0,0,0,0, 1.f}, {1, 0,-1,-1, 0,0,0,0, 1.f}, {1, 1,-1,-1, 0,0,0,0, 1.f},
    {1,-1, 0, 0, 0,0,0,0, 1.f}, {1, 0, 0, 0, 0,0,0,0, 1.f}, {1, 1, 0, 0, 0,0,0,0, 1.f},
    {1,-1, 1, 1, 0,0,0,0, 1.f}, {1, 0, 1, 1, 0,0,0,0, 1.f}, {1, 1, 1, 1, 0,0,0,0, 1.f},
    // ring5 (16)
    {1,-2,-2, 2, 1,-2,-1, 2, 1.f/9.f},
    {1,-1,-2, 2, 0,0,0,0, 0.2f},
    {1, 0,-2, 2, 0,0,0,0, 0.2f},
    {1, 1,-2, 2, 0,0,0,0, 0.2f},
    {1, 2,-2, 2, 1,-2,-2, 1, 1.f/9.f},
    {0,0,0,0, 1,-1,-2, 2, 0.2f},
    {0,0,0,0, 1,-1,-2, 2, 0.2f},
    {0,0,0,0, 1, 0,-2, 2, 0.2f},
    {0,0,0,0, 1, 0,-2, 2, 0.2f},
    {0,0,0,0, 1, 1,-2, 2, 0.2f},
    {0,0,0,0, 1, 1,-2, 2, 0.2f},
    {1,-2,-2, 2, 1, 2,-1, 2, 1.f/9.f},
    {1,-1,-2, 2, 0,0,0,0, 0.2f},
    {1, 0,-2, 2, 0,0,0,0, 0.2f},
    {1, 1,-2, 2, 0,0,0,0, 0.2f},
    {1, 2,-2, 2, 1, 2,-2, 1, 1.f/9.f},
    // ring7 (24)
    {1,-3,-3,11, 1,-3,-2,21, 1.f/39.f},
    {1,-2,-3,11, 0,0,0,0, 1.f/15.f},
    {1,-1,-3,11, 0,0,0,0, 1.f/15.f},
    {1, 0,-3,11, 0,0,0,0, 1.f/15.f},
    {1, 1,-3,11, 0,0,0,0, 1.f/15.f},
    {1, 2,-3,11, 0,0,0,0, 1.f/15.f},
    {1, 3,-3,11, 1,-3,-21, 2, 1.f/39.f},
    {0,0,0,0, 1,-2,-3,21, 0.04f},
    {0,0,0,0, 1,-2,-21,3, 0.04f},
    {0,0,0,0, 1,-1,-3,21, 0.04f},
    {0,0,0,0, 1,-1,-21,3, 0.04f},
    {0,0,0,0, 1, 0,-3,21, 0.04f},
    {0,0,0,0, 1, 0,-21,3, 0.04f},
    {0,0,0,0, 1, 1,-3,21, 0.04f},
    {0,0,0,0, 1, 1,-21,3, 0.04f},
    {0,0,0,0, 1, 2,-3,21, 0.04f},
    {0,0,0,0, 1, 2,-21,3, 0.04f},
    {1,-3,-11,3, 1, 3,-2,21, 1.f/39.f},
    {1,-2,-11,3, 0,0,0,0, 1.f/15.f},
    {1,-1,-11,3, 0,0,0,0, 1.f/15.f},
    {1, 0,-11,3, 0,0,0,0, 1.f/15.f},
    {1, 1,-11,3, 0,0,0,0, 1.f/15.f},
    {1, 2,-11,3, 0,0,0,0, 1.f/15.f},
    {1, 3,-11,3, 1, 3,-21,2, 1.f/39.f},
};

// reflect-pad(3) + clip index map; valid for u in [-21, 212]
__device__ __forceinline__ int mapIdx(int u) {
    if (u < 0) { u = -u; if (u > 3) u = 3; }
    else if (u > 191) { u = 382 - u; if (u < 188) u = 188; }
    return u;
}

// RNE fp32->bf16 bits via native conversion (compiler fuses pairs to v_cvt_pk_bf16_f32)
__device__ __forceinline__ ushort f2bf(float f) {
    __hip_bfloat16 h = __float2bfloat16(f);
    return __builtin_bit_cast(ushort, h);
}

// LDS: aliased region { E flat[1924]f (7696 B) | PVt[27][38]f @7696 | PHt[10][76]f @11808 }
//      sized by featB[128][66]u16 = 16896 B; wlds[64][72]u16 @16896 (9216 B). Total 26112 B.
constexpr int OFF_PVT  = 7696;
constexpr int OFF_PHT  = 11808;
constexpr int OFF_WLDS = 16896;
constexpr int SM_BYTES = 26112;

// NC = channels per block (8 split / 16 direct); DIRECT: write out+bias, else partial to dst.
template<int NC, bool DIRECT>
__global__ __launch_bounds__(NT, 3)
void fova13(const float* __restrict__ x, const float* __restrict__ wgt,
            const float* __restrict__ bias, float* __restrict__ dst)
{
    constexpr int HALVES = Cc / NC;
    __shared__ __align__(16) char smraw[SM_BYTES];
    float*  Ef          = reinterpret_cast<float*>(smraw);                 // [26*74] flat
    float  (*PVt)[38]   = reinterpret_cast<float(*)[38]>(smraw + OFF_PVT);
    float  (*PHt)[76]   = reinterpret_cast<float(*)[76]>(smraw + OFF_PHT);
    ushort (*featB)[66] = reinterpret_cast<ushort(*)[66]>(smraw);          // aliases E/PVt/PHt
    ushort (*wlds)[72]  = reinterpret_cast<ushort(*)[72]>(smraw + OFF_WLDS);
    ushort* Wf          = reinterpret_cast<ushort*>(smraw + OFF_WLDS);

    const int tid  = threadIdx.x;
    const int lane = tid & 63;
    const int wv   = tid >> 6;          // wave id 0/1
    const int w0   = blockIdx.x * TW;
    const int h0   = blockIdx.y * TH;
    const int bz   = blockIdx.z;
    const int b    = (HALVES == 1) ? bz : (bz >> 1);
    const int half = (HALVES == 1) ? 0  : (bz & 1);
    const int c0   = half * NC;
    const int ph   = tid >> 5;          // pixel row 0..3 (tid == pixel id)
    const int pw   = tid & 31;
    const int ur   = ph + 11;           // pixel row in extended coords
    const int vcc  = pw + 21;           // pixel col in extended coords

    // ---- E staging addresses (c-invariant, division-free) ----
    int egoff[16];
    {
        int uu = (tid >= 74) ? 1 : 0;
        int vv = tid - 74 * uu;
#pragma unroll
        for (int k = 0; k < 16; ++k) {
            if (tid + k * NT < 1924) {
                egoff[k] = mapIdx(h0 + uu - 11) * Ww + mapIdx(w0 + vv - 21);
                vv += 54;
                if (vv >= 74) { vv -= 74; uu += 2; } else { uu += 1; }
            } else egoff[k] = 0;
        }
    }
    // ---- W staging start indices (incremental, no division) ----
    const int o0w   = (tid >= 98) ? 2 : (tid >= 49 ? 1 : 0);
    const int f0w   = tid - o0w * 49;
    const int boff0 = o0w * 784 + f0w;
    const int loff0 = o0w * 72 + f0w;

    float4v acc[4][4];
#pragma unroll
    for (int i = 0; i < 4; ++i)
#pragma unroll
        for (int j = 0; j < 4; ++j) acc[i][j] = (float4v)(0.f);

    if (tid < 64) {
#pragma unroll
        for (int f = 49; f < 64; ++f) wlds[tid][f] = 0;
    }

    const float* xb = x + ((size_t)b * Cc + c0) * HW;

    for (int cc = 0; cc < NC; ++cc) {
        const int c = c0 + cc;
        // ---- phase 1: stage E(c) + W(c) into LDS (division-free) ----
        {
            const float* xp = xb + cc * HW;
#pragma unroll
            for (int k = 0; k < 16; ++k)
                if (tid + k * NT < 1924) Ef[tid + k * NT] = xp[egoff[k]];

            const float* wc = wgt + c * 49;
            int ff = f0w, bo = boff0, lo = loff0;
#pragma unroll
            for (int k = 0; k < 25; ++k) {
                if (tid + k * NT < 3136) {
                    Wf[lo] = f2bf(wc[bo]);
                    if (ff >= 19) { ff -= 19; bo += 2333; lo += 197; }
                    else          { ff += 30; bo += 1598; lo += 174; }
                }
            }
        }
        __syncthreads();

        // ---- phase 2: serial prefix scans ----
        if (tid < 38) {
            const int cv = tid;           // abs col 18+cv
            float r = 0.f;
            PVt[0][cv] = 0.f;
#pragma unroll
            for (int rr = 0; rr < 26; ++rr) { r += Ef[rr * 74 + 18 + cv]; PVt[rr + 1][cv] = r; }
        }
        if (tid >= 96 && tid < 106) {
            const int rv = tid - 96;      // abs row 8+rv
            float r = 0.f;
            PHt[rv][0] = 0.f;
#pragma unroll
            for (int s = 0; s < 74; ++s) { r += Ef[(8 + rv) * 74 + s]; PHt[rv][s + 1] = r; }
        }
        __syncthreads();

        // ---- phase 3a: features into registers ----
        float feat[49];
#pragma unroll
        for (int f = 0; f < 49; ++f) {
            float s = 0.f;
            if (FT[f].hasV) {
                int cv = pw + 3 + FT[f].vdj;
                s += PVt[ur + FT[f].vi1 + 1][cv] - PVt[ur + FT[f].vi0][cv];
            }
            if (FT[f].hasH) {
                int rv = ph + 3 + FT[f].hdi;
                s += PHt[rv][vcc + FT[f].hj1 + 1] - PHt[rv][vcc + FT[f].hj0];
            }
            feat[f] = s * FT[f].inv_n;
        }
        __syncthreads();   // all E/PVt/PHt reads complete before featB overwrites them

        // ---- phase 3b: write featB (packed b32; pairs fuse to v_cvt_pk_bf16_f32) ----
        {
            uint* fb32 = reinterpret_cast<uint*>(&featB[tid][0]);
#pragma unroll
            for (int j = 0; j < 24; ++j)
                fb32[j] = (uint)f2bf(feat[2 * j]) | ((uint)f2bf(feat[2 * j + 1]) << 16);
            featB[tid][48] = f2bf(feat[48]);
#pragma unroll
            for (int f = 49; f < 64; ++f) featB[tid][f] = 0;
        }
        __syncthreads();

        // ---- phase 4: contraction via MFMA (A from wlds b128, B from featB) ----
        {
            const int olo = lane & 15, kg = lane >> 4;
#pragma unroll
            for (int kc = 0; kc < 2; ++kc) {
                const int k0 = kc * 32 + kg * 8;          // 16B aligned in wlds (stride 72)
                short8v afr[4];
#pragma unroll
                for (int ob = 0; ob < 4; ++ob) {
                    const int o = ob * 16 + olo;
                    afr[ob] = *(const short8v*)(&wlds[o][k0]);
                }
                short8v bfr[4];
#pragma unroll
                for (int nb = 0; nb < 4; ++nb) {
                    const int p = wv * 64 + nb * 16 + olo;
                    const uint* bp = (const uint*)(&featB[p][k0]);
                    uint4 u;
                    u.x = bp[0]; u.y = bp[1]; u.z = bp[2]; u.w = bp[3];
                    bfr[nb] = __builtin_bit_cast(short8v, u);
                }
#pragma unroll
                for (int ob = 0; ob < 4; ++ob)
#pragma unroll
                    for (int nb = 0; nb < 4; ++nb)
                        acc[ob][nb] = __builtin_amdgcn_mfma_f32_16x16x32_bf16(
                            afr[ob], bfr[nb], acc[ob][nb], 0, 0, 0);
            }
        }
        __syncthreads();   // featB (aliased with E) fully read before next stage
    }

    // ---- epilogue: plain stores (partial or final) ----
    float* dbase = DIRECT ? dst : (dst + (size_t)half * PLANE);
#pragma unroll
    for (int ob = 0; ob < 4; ++ob)
#pragma unroll
        for (int nb = 0; nb < 4; ++nb) {
            const int p = wv * 64 + nb * 16 + (lane & 15);
            const int h = h0 + (p >> 5), w = w0 + (p & 31);
            const int o0 = ob * 16 + ((lane >> 4) << 2);
            float4v a = acc[ob][nb];
#pragma unroll
            for (int r = 0; r < 4; ++r) {
                const int o = o0 + r;
                float v = DIRECT ? (a[r] + bias[o]) : a[r];
                dbase[(((size_t)b * Oo + o) * Hh + h) * Ww + w] = v;
            }
        }
}

// out = p0 + p1 + bias (memory-bound, float4)
__global__ __launch_bounds__(256)
void reduce2(const float4* __restrict__ p, const float* __restrict__ bias,
             float4* __restrict__ out)
{
    const int n4 = (int)(PLANE / 4);            // 2359296
    const int p1off = n4;
    for (int i = blockIdx.x * 256 + threadIdx.x; i < n4; i += gridDim.x * 256) {
        float4 a = p[i];
        float4 b = p[i + p1off];
        const int o = (i / 9216) & 63;          // 9216 float4s per (b,o) plane
        const float bo = bias[o];
        float4 r;
        r.x = a.x + b.x + bo; r.y = a.y + b.y + bo;
        r.z = a.z + b.z + bo; r.w = a.w + b.w + bo;
        out[i] = r;
    }
}

} // namespace

extern "C" void kernel_launch(void* const* d_in, const int* in_sizes, int n_in,
                              void* d_out, int out_size, void* d_ws, size_t ws_size,
                              hipStream_t stream) {
    (void)in_sizes; (void)n_in; (void)out_size;
    const float* x    = (const float*)d_in[0];
    const float* wgt  = (const float*)d_in[1];
    const float* bias = (const float*)d_in[2];
    float* out        = (float*)d_out;

    const size_t need = 2 * PLANE * sizeof(float);   // 75.5 MB of partials
    dim3 block(NT);
    if (ws_size >= need) {
        float* part = (float*)d_ws;
        dim3 grid(Ww / TW, Hh / TH, Bb * 2);         // 2304 blocks, 8 channels each
        fova13<8, false><<<grid, block, 0, stream>>>(x, wgt, bias, part);
        reduce2<<<dim3(4096), dim3(256), 0, stream>>>((const float4*)part, bias, (float4*)out);
    } else {
        dim3 grid(Ww / TW, Hh / TH, Bb);             // 1152 blocks, 16 channels each
        fova13<16, true><<<grid, block, 0, stream>>>(x, wgt, bias, out);
    }
}

// Round 14
// 214.332 us; speedup vs baseline: 5.1407x; 5.1407x over previous
//
#include <hip/hip_runtime.h>
#include <hip/hip_bf16.h>

typedef __attribute__((ext_vector_type(8))) short short8v;   // bf16x8 fragment
typedef __attribute__((ext_vector_type(4))) float float4v;   // fp32x4 accum
typedef unsigned short ushort;
typedef unsigned int uint;

namespace {

constexpr int Hh = 192, Ww = 192, Cc = 16, Oo = 64, Bb = 4;
constexpr int TH = 4, TW = 32, NT = 128;     // 4x32 pixel tile, 128 threads (2 waves)
constexpr int HW = Hh * Ww;                  // 36864
constexpr size_t PLANE = (size_t)Bb * Oo * HW;   // 9437184 floats per partial

// Each feature = (vertical segment sum) + (horizontal segment sum), scaled by 1/n.
struct FD { int hasV; int vdj, vi0, vi1; int hasH; int hdi, hj0, hj1; float inv_n; };

constexpr FD FT[49] = {
    // 9 inner taps (i,j) row-major, n=1
    {1,-1,-1,-1, 0,0,0,0, 1.f}, {1, 0,-1,-1, 0,0,0,0, 1.f}, {1, 1,-1,-1, 0,0,0,0, 1.f},
    {1,-1, 0, 0, 0,0,0,0, 1.f}, {1, 0, 0, 0, 0,0,0,0, 1.f}, {1, 1, 0, 0, 0,0,0,0, 1.f},
    {1,-1, 1, 1, 0,0,0,0, 1.f}, {1, 0, 1, 1, 0,0,0,0, 1.f}, {1, 1, 1, 1, 0,0,0,0, 1.f},
    // ring5 (16)
    {1,-2,-2, 2, 1,-2,-1, 2, 1.f/9.f},
    {1,-1,-2, 2, 0,0,0,0, 0.2f},
    {1, 0,-2, 2, 0,0,0,0, 0.2f},
    {1, 1,-2, 2, 0,0,0,0, 0.2f},
    {1, 2,-2, 2, 1,-2,-2, 1, 1.f/9.f},
    {0,0,0,0, 1,-1,-2, 2, 0.2f},
    {0,0,0,0, 1,-1,-2, 2, 0.2f},
    {0,0,0,0, 1, 0,-2, 2, 0.2f},
    {0,0,0,0, 1, 0,-2, 2, 0.2f},
    {0,0,0,0, 1, 1,-2, 2, 0.2f},
    {0,0,0,0, 1, 1,-2, 2, 0.2f},
    {1,-2,-2, 2, 1, 2,-1, 2, 1.f/9.f},
    {1,-1,-2, 2, 0,0,0,0, 0.2f},
    {1, 0,-2, 2, 0,0,0,0, 0.2f},
    {1, 1,-2, 2, 0,0,0,0, 0.2f},
    {1, 2,-2, 2, 1, 2,-2, 1, 1.f/9.f},
    // ring7 (24)
    {1,-3,-3,11, 1,-3,-2,21, 1.f/39.f},
    {1,-2,-3,11, 0,0,0,0, 1.f/15.f},
    {1,-1,-3,11, 0,0,0,0, 1.f/15.f},
    {1, 0,-3,11, 0,0,0,0, 1.f/15.f},
    {1, 1,-3,11, 0,0,0,0, 1.f/15.f},
    {1, 2,-3,11, 0,0,0,0, 1.f/15.f},
    {1, 3,-3,11, 1,-3,-21, 2, 1.f/39.f},
    {0,0,0,0, 1,-2,-3,21, 0.04f},
    {0,0,0,0, 1,-2,-21,3, 0.04f},
    {0,0,0,0, 1,-1,-3,21, 0.04f},
    {0,0,0,0, 1,-1,-21,3, 0.04f},
    {0,0,0,0, 1, 0,-3,21, 0.04f},
    {0,0,0,0, 1, 0,-21,3, 0.04f},
    {0,0,0,0, 1, 1,-3,21, 0.04f},
    {0,0,0,0, 1, 1,-21,3, 0.04f},
    {0,0,0,0, 1, 2,-3,21, 0.04f},
    {0,0,0,0, 1, 2,-21,3, 0.04f},
    {1,-3,-11,3, 1, 3,-2,21, 1.f/39.f},
    {1,-2,-11,3, 0,0,0,0, 1.f/15.f},
    {1,-1,-11,3, 0,0,0,0, 1.f/15.f},
    {1, 0,-11,3, 0,0,0,0, 1.f/15.f},
    {1, 1,-11,3, 0,0,0,0, 1.f/15.f},
    {1, 2,-11,3, 0,0,0,0, 1.f/15.f},
    {1, 3,-11,3, 1, 3,-21,2, 1.f/39.f},
};

// reflect-pad(3) + clip index map; valid for u in [-21, 212]
__device__ __forceinline__ int mapIdx(int u) {
    if (u < 0) { u = -u; if (u > 3) u = 3; }
    else if (u > 191) { u = 382 - u; if (u < 188) u = 188; }
    return u;
}

// RNE fp32->bf16 bits (native; pairs fuse to v_cvt_pk_bf16_f32)
__device__ __forceinline__ ushort f2bf(float f) {
    __hip_bfloat16 h = __float2bfloat16(f);
    return __builtin_bit_cast(ushort, h);
}

// LDS layout (bytes): union { E[26][76]f (7904) | PVt[27][40]f (+4320) | PHt[10][76]f (+3040) }
//                     aliased with featB[128][66]u16 (16896)  -> region size 16896
// wlds[64][72]u16 (9216 B) separate.  Total 26112 B -> 6 blocks/CU LDS-wise.
constexpr int OFF_PVT = 26 * 76 * 4;              // 7904
constexpr int OFF_PHT = OFF_PVT + 27 * 40 * 4;    // 12224
constexpr int SM_BYTES = 128 * 66 * 2;            // 16896

// NC = channels per block; DIRECT: write out+bias, else fp32 partial to dst.
template<int NC, bool DIRECT>
__global__ __launch_bounds__(NT, 3)
void fova14(const float* __restrict__ x, const float* __restrict__ wgt,
            const float* __restrict__ bias, float* __restrict__ dst)
{
    constexpr int HALVES = Cc / NC;
    __shared__ __align__(16) char smraw[SM_BYTES];
    __shared__ ushort wlds[64][72];    // bf16 weight slice [o][k], 144B rows (16B-aligned)

    float (*E)[76]      = reinterpret_cast<float(*)[76]>(smraw);
    float (*PVt)[40]    = reinterpret_cast<float(*)[40]>(smraw + OFF_PVT);
    float (*PHt)[76]    = reinterpret_cast<float(*)[76]>(smraw + OFF_PHT);
    ushort (*featB)[66] = reinterpret_cast<ushort(*)[66]>(smraw);

    const int tid  = threadIdx.x;
    const int lane = tid & 63;
    const int wv   = tid >> 6;          // wave id 0/1
    const int w0   = blockIdx.x * TW;
    const int h0   = blockIdx.y * TH;
    const int bz   = blockIdx.z;
    const int b    = (HALVES == 1) ? bz : (bz >> 1);
    const int half = (HALVES == 1) ? 0  : (bz & 1);
    const int c0   = half * NC;
    const int ph   = tid >> 5;          // pixel row 0..3 (tid == pixel id)
    const int pw   = tid & 31;
    const int ur   = ph + 11;           // pixel row in extended coords
    const int vcc  = pw + 21;           // pixel col in extended coords

    float4v acc[4][4];
#pragma unroll
    for (int i = 0; i < 4; ++i)
#pragma unroll
        for (int j = 0; j < 4; ++j) acc[i][j] = (float4v)(0.f);

    // one-time: zero weight pad slots k=49..63 (never rewritten)
    if (tid < 64) {
#pragma unroll
        for (int f = 49; f < 64; ++f) wlds[tid][f] = 0;
    }

    for (int cc = 0; cc < NC; ++cc) {
        const int c = c0 + cc;
        // ---- phase 1: stage E(c) + stage W(c) into LDS (R8-verbatim divisions) ----
        {
            const float* xp = x + (size_t)(b * Cc + c) * HW;
            for (int idx = tid; idx < 26 * 74; idx += NT) {
                int uu = idx / 74, vvv = idx - uu * 74;
                E[uu][vvv] = xp[mapIdx(h0 + uu - 11) * Ww + mapIdx(w0 + vvv - 21)];
            }
            const float* wc = wgt + c * 49;
            for (int idx = tid; idx < 64 * 49; idx += NT) {
                int o = idx / 49, f = idx - o * 49;
                wlds[o][f] = f2bf(wc[o * 784 + f]);
            }
        }
        __syncthreads();

        // ---- phase 2: serial prefix scans ----
        if (tid < 38) {
            const int cv = tid;           // abs col 18+cv
            float r = 0.f;
            PVt[0][cv] = 0.f;
#pragma unroll
            for (int rr = 0; rr < 26; ++rr) { r += E[rr][18 + cv]; PVt[rr + 1][cv] = r; }
        }
        if (tid >= 96 && tid < 106) {
            const int rv = tid - 96;      // abs row 8+rv
            float r = 0.f;
            PHt[rv][0] = 0.f;
#pragma unroll
            for (int s = 0; s < 74; ++s) { r += E[8 + rv][s]; PHt[rv][s + 1] = r; }
        }
        __syncthreads();

        // ---- phase 3a: features into registers ----
        float feat[49];
        {
#pragma unroll
            for (int f = 0; f < 49; ++f) {
                float s = 0.f;
                if (FT[f].hasV) {
                    int cv = pw + 3 + FT[f].vdj;
                    s += PVt[ur + FT[f].vi1 + 1][cv] - PVt[ur + FT[f].vi0][cv];
                }
                if (FT[f].hasH) {
                    int rv = ph + 3 + FT[f].hdi;
                    s += PHt[rv][vcc + FT[f].hj1 + 1] - PHt[rv][vcc + FT[f].hj0];
                }
                feat[f] = s * FT[f].inv_n;
            }
        }
        __syncthreads();   // all E/PVt/PHt reads complete before featB overwrites them

        // ---- phase 3b: write featB (aliases E/PVt/PHt region) ----
        {
            uint* fb32 = reinterpret_cast<uint*>(&featB[tid][0]);
#pragma unroll
            for (int j = 0; j < 24; ++j)
                fb32[j] = (uint)f2bf(feat[2 * j]) | ((uint)f2bf(feat[2 * j + 1]) << 16);
            featB[tid][48] = f2bf(feat[48]);
#pragma unroll
            for (int f = 49; f < 64; ++f) featB[tid][f] = 0;
        }
        __syncthreads();

        // ---- phase 4: contraction via MFMA (A from wlds b128, B from featB) ----
        {
            const int olo = lane & 15, kg = lane >> 4;
#pragma unroll
            for (int kc = 0; kc < 2; ++kc) {
                const int k0 = kc * 32 + kg * 8;          // 16B aligned in wlds
                short8v afr[4];
#pragma unroll
                for (int ob = 0; ob < 4; ++ob) {
                    const int o = ob * 16 + olo;
                    afr[ob] = *(const short8v*)(&wlds[o][k0]);
                }
                short8v bfr[4];
#pragma unroll
                for (int nb = 0; nb < 4; ++nb) {
                    const int p = wv * 64 + nb * 16 + olo;
                    const uint* bp = (const uint*)(&featB[p][k0]);
                    uint4 u;
                    u.x = bp[0]; u.y = bp[1]; u.z = bp[2]; u.w = bp[3];
                    bfr[nb] = __builtin_bit_cast(short8v, u);
                }
#pragma unroll
                for (int ob = 0; ob < 4; ++ob)
#pragma unroll
                    for (int nb = 0; nb < 4; ++nb)
                        acc[ob][nb] = __builtin_amdgcn_mfma_f32_16x16x32_bf16(
                            afr[ob], bfr[nb], acc[ob][nb], 0, 0, 0);
            }
        }
        __syncthreads();   // featB (aliased with E) fully read before next stage
    }

    // ---- epilogue: plain stores (partial or final) ----
    float* dbase = DIRECT ? dst : (dst + (size_t)half * PLANE);
#pragma unroll
    for (int ob = 0; ob < 4; ++ob)
#pragma unroll
        for (int nb = 0; nb < 4; ++nb) {
            const int p = wv * 64 + nb * 16 + (lane & 15);
            const int h = h0 + (p >> 5), w = w0 + (p & 31);
            const int o0 = ob * 16 + ((lane >> 4) << 2);
            float4v a = acc[ob][nb];
#pragma unroll
            for (int r = 0; r < 4; ++r) {
                const int o = o0 + r;
                float v = DIRECT ? (a[r] + bias[o]) : a[r];
                dbase[(((size_t)b * Oo + o) * Hh + h) * Ww + w] = v;
            }
        }
}

// out = p0 + p1 + bias (memory-bound, float4, grid-stride)
__global__ __launch_bounds__(256)
void reduce2(const float4* __restrict__ p, const float* __restrict__ bias,
             float4* __restrict__ out)
{
    const int n4 = (int)(PLANE / 4);            // 2359296
    for (int i = blockIdx.x * 256 + threadIdx.x; i < n4; i += gridDim.x * 256) {
        float4 a = p[i];
        float4 b = p[i + n4];
        const int o = (i / 9216) & 63;          // 9216 float4s per (b,o) plane
        const float bo = bias[o];
        float4 r;
        r.x = a.x + b.x + bo; r.y = a.y + b.y + bo;
        r.z = a.z + b.z + bo; r.w = a.w + b.w + bo;
        out[i] = r;
    }
}

} // namespace

extern "C" void kernel_launch(void* const* d_in, const int* in_sizes, int n_in,
                              void* d_out, int out_size, void* d_ws, size_t ws_size,
                              hipStream_t stream) {
    (void)in_sizes; (void)n_in; (void)out_size;
    const float* x    = (const float*)d_in[0];
    const float* wgt  = (const float*)d_in[1];
    const float* bias = (const float*)d_in[2];
    float* out        = (float*)d_out;

    const size_t need = 2 * PLANE * sizeof(float);   // 75.5 MB of partials
    dim3 block(NT);
    if (ws_size >= need) {
        float* part = (float*)d_ws;
        dim3 grid(Ww / TW, Hh / TH, Bb * 2);         // 2304 blocks, 8 channels each
        fova14<8, false><<<grid, block, 0, stream>>>(x, wgt, bias, part);
        reduce2<<<dim3(2048), dim3(256), 0, stream>>>((const float4*)part, bias, (float4*)out);
    } else {
        dim3 grid(Ww / TW, Hh / TH, Bb);             // 1152 blocks, 16 channels each
        fova14<16, true><<<grid, block, 0, stream>>>(x, wgt, bias, out);
    }
}